// Round 2
// baseline (22592.604 us; speedup 1.0000x reference)
//
#include <hip/hip_runtime.h>
#include <hip/hip_bf16.h>

// GRU restructured:
//   Phase 0: fp32->bf16 weight conversion; gate weights split into h-part/x-part.
//   Phase 1: Pg[b,t,:] = word[b,t-1,:] @ Wg_x.T + bg  (parallel GEMM; t==0 -> bias only)
//            Pz -> d_out (scratch, dead before out_gemm), Pr -> ws, Ph -> ws (PhH, in-place).
//   Phase 2: persistent kernel (plain launch, 256 WGs = 256 CUs, 1 WG/CU via 132KB LDS):
//            4 batch-groups x 64 WGs; per step:
//              stage A: z,r = sigmoid(h @ W{z,r}h.T + P); write z, r*h to small global bufs
//              stage B: htilde = tanh(rh @ Whh.T + PhH[t]); h = (1-z)h + z*htilde -> PhH[t]
//            2 group-scoped global barriers per step (monotonic counter, rel/acq, agent).
//   Phase 3: out = PhH @ Wy.T + by (parallel GEMM, fp32 out -> d_out).

#define EMB 512
#define HID 1024
#define BATCHN 64
#define TLEN 512
#define CAT 1536
#define GROUPS 4
#define GB 16
#define RWGS 64
#define PADW (HID + 8)
#define GPAD 8

typedef __attribute__((ext_vector_type(8))) short bf16x8;
typedef __attribute__((ext_vector_type(4))) short s16x4;
typedef __attribute__((ext_vector_type(4))) float f32x4;
typedef unsigned int u32;
typedef unsigned long long u64;
typedef unsigned short u16;

__device__ __forceinline__ float bf2f(u16 u) {
  union { float f; u32 i; } v; v.i = ((u32)u) << 16; return v.f;
}
__device__ __forceinline__ u16 f2bf(float f) {
  union { float f; u32 i; } v; v.f = f;
  u32 r = v.i + 0x7fffu + ((v.i >> 16) & 1u);
  return (u16)(r >> 16);
}

// ---------------- phase 0: weight conversion ----------------
__global__ __launch_bounds__(256) void convert_gate_w(const float* __restrict__ W,
                                                      u16* __restrict__ Wh_,
                                                      u16* __restrict__ Wx_) {
  int i = blockIdx.x * 256 + threadIdx.x;
  if (i >= HID * CAT) return;
  int row = i / CAT, col = i - row * CAT;
  u16 v = f2bf(W[i]);
  if (col < HID) Wh_[row * HID + col] = v;
  else           Wx_[row * EMB + (col - HID)] = v;
}

__global__ __launch_bounds__(256) void convert_wy(const float* __restrict__ W, u16* __restrict__ Wy_) {
  int i = blockIdx.x * 256 + threadIdx.x;
  if (i < EMB * HID) Wy_[i] = f2bf(W[i]);
}

// ---------------- phase 1: P = shift(word) @ Wx.T + bias ----------------
__global__ __launch_bounds__(256) void proj_kernel(const float* __restrict__ word,
                                                   const u16* __restrict__ Wx,
                                                   const float* __restrict__ bias,
                                                   u16* __restrict__ P) {
  __shared__ __align__(16) u16 As[64][64 + GPAD];
  __shared__ __align__(16) u16 Bs[64][64 + GPAD];
  const int tid = threadIdx.x;
  const int wid = tid >> 6, lane = tid & 63;
  const int m0 = blockIdx.x * 64, n0 = blockIdx.y * 64;
  const int mw = (wid >> 1) * 32, nw = (wid & 1) * 32;
  f32x4 acc[2][2] = {};
  for (int k0 = 0; k0 < EMB; k0 += 64) {
#pragma unroll
    for (int it = 0; it < 4; ++it) {
      int e = (it * 256 + tid) * 4;
      int row = e >> 6, col = e & 63;
      int R = m0 + row;
      float4 a = make_float4(0.f, 0.f, 0.f, 0.f);
      if ((R & (TLEN - 1)) != 0)
        a = *reinterpret_cast<const float4*>(&word[(u64)(R - 1) * EMB + k0 + col]);
      s16x4 vv;
      vv[0] = (short)f2bf(a.x); vv[1] = (short)f2bf(a.y);
      vv[2] = (short)f2bf(a.z); vv[3] = (short)f2bf(a.w);
      *reinterpret_cast<s16x4*>(&As[row][col]) = vv;
    }
#pragma unroll
    for (int it = 0; it < 2; ++it) {
      int e = (it * 256 + tid) * 8;
      int row = e >> 6, col = e & 63;
      *reinterpret_cast<bf16x8*>(&Bs[row][col]) =
          *reinterpret_cast<const bf16x8*>(&Wx[(u64)(n0 + row) * EMB + k0 + col]);
    }
    __syncthreads();
#pragma unroll
    for (int kk = 0; kk < 2; ++kk) {
      const int kb = kk * 32 + 8 * (lane >> 4);
#pragma unroll
      for (int i = 0; i < 2; ++i) {
        bf16x8 a = *reinterpret_cast<const bf16x8*>(&As[mw + i * 16 + (lane & 15)][kb]);
#pragma unroll
        for (int j = 0; j < 2; ++j) {
          bf16x8 b = *reinterpret_cast<const bf16x8*>(&Bs[nw + j * 16 + (lane & 15)][kb]);
          acc[i][j] = __builtin_amdgcn_mfma_f32_16x16x32_bf16(a, b, acc[i][j], 0, 0, 0);
        }
      }
    }
    __syncthreads();
  }
#pragma unroll
  for (int i = 0; i < 2; ++i)
#pragma unroll
    for (int j = 0; j < 2; ++j) {
      int col = n0 + nw + j * 16 + (lane & 15);
      float bv = bias[col];
#pragma unroll
      for (int q = 0; q < 4; ++q) {
        int row = m0 + mw + i * 16 + 4 * (lane >> 4) + q;
        P[(u64)row * HID + col] = f2bf(acc[i][j][q] + bv);
      }
    }
}

// ---------------- phase 3: out = H @ Wy.T + by (fp32 out) ----------------
__global__ __launch_bounds__(256) void out_gemm(const u16* __restrict__ H,
                                                const u16* __restrict__ Wy,
                                                const float* __restrict__ by,
                                                float* __restrict__ out) {
  __shared__ __align__(16) u16 As[64][64 + GPAD];
  __shared__ __align__(16) u16 Bs[64][64 + GPAD];
  const int tid = threadIdx.x;
  const int wid = tid >> 6, lane = tid & 63;
  const int m0 = blockIdx.x * 64, n0 = blockIdx.y * 64;
  const int mw = (wid >> 1) * 32, nw = (wid & 1) * 32;
  f32x4 acc[2][2] = {};
  for (int k0 = 0; k0 < HID; k0 += 64) {
#pragma unroll
    for (int it = 0; it < 2; ++it) {
      int e = (it * 256 + tid) * 8;
      int row = e >> 6, col = e & 63;
      *reinterpret_cast<bf16x8*>(&As[row][col]) =
          *reinterpret_cast<const bf16x8*>(&H[(u64)(m0 + row) * HID + k0 + col]);
      *reinterpret_cast<bf16x8*>(&Bs[row][col]) =
          *reinterpret_cast<const bf16x8*>(&Wy[(u64)(n0 + row) * HID + k0 + col]);
    }
    __syncthreads();
#pragma unroll
    for (int kk = 0; kk < 2; ++kk) {
      const int kb = kk * 32 + 8 * (lane >> 4);
#pragma unroll
      for (int i = 0; i < 2; ++i) {
        bf16x8 a = *reinterpret_cast<const bf16x8*>(&As[mw + i * 16 + (lane & 15)][kb]);
#pragma unroll
        for (int j = 0; j < 2; ++j) {
          bf16x8 b = *reinterpret_cast<const bf16x8*>(&Bs[nw + j * 16 + (lane & 15)][kb]);
          acc[i][j] = __builtin_amdgcn_mfma_f32_16x16x32_bf16(a, b, acc[i][j], 0, 0, 0);
        }
      }
    }
    __syncthreads();
  }
#pragma unroll
  for (int i = 0; i < 2; ++i)
#pragma unroll
    for (int j = 0; j < 2; ++j) {
      int col = n0 + nw + j * 16 + (lane & 15);
      float bv = by[col];
#pragma unroll
      for (int q = 0; q < 4; ++q) {
        int row = m0 + mw + i * 16 + 4 * (lane >> 4) + q;
        out[(u64)row * EMB + col] = acc[i][j][q] + bv;
      }
    }
}

// ---------------- phase 2: persistent recurrent kernel ----------------
// Group barrier: monotonic counter, one arrival per WG (thread 0).
// Release: __threadfence() (writes back local caches) before the atomic add.
// Acquire: spin with acquire load, then an agent-scope acquire fence by ALL
// threads (invalidate stale vector-cache lines; weights live in LDS so this
// costs nothing in reuse).
__device__ __forceinline__ void group_barrier(u32* ctr, u32 target) {
  __syncthreads();
  if (threadIdx.x == 0) {
    __threadfence();
    __hip_atomic_fetch_add(ctr, 1u, __ATOMIC_RELEASE, __HIP_MEMORY_SCOPE_AGENT);
    while (__hip_atomic_load(ctr, __ATOMIC_ACQUIRE, __HIP_MEMORY_SCOPE_AGENT) < target) {
      __builtin_amdgcn_s_sleep(1);
    }
  }
  __syncthreads();
  __builtin_amdgcn_fence(__ATOMIC_ACQUIRE, "agent");
}

__global__ __launch_bounds__(256) void gru_persistent(
    const u16* __restrict__ Wzh, const u16* __restrict__ Wrh, const u16* __restrict__ Whh,
    const u16* __restrict__ Pz, const u16* __restrict__ Pr, u16* __restrict__ PhH,
    u16* __restrict__ zbuf, u16* __restrict__ rhbuf, u32* bar) {
  // LDS: WA 64.5K + WB 32.25K + HX 32.25K + RED 3K = 132K -> 1 WG/CU, grid 256 = #CUs.
  __shared__ __align__(16) u16 WA[32 * PADW];
  __shared__ __align__(16) u16 WB[16 * PADW];
  __shared__ __align__(16) u16 HX[16 * PADW];
  __shared__ __align__(16) float RED[3 * 64 * 4];

  const int tid = threadIdx.x;
  const int wid = tid >> 6;
  const int lane = tid & 63;
  const int g = blockIdx.x & (GROUPS - 1);   // groups interleave -> 2 XCDs per group
  const int rank = blockIdx.x >> 2;
  const int b0 = g * GB;
  const bool isz = (rank < 32);
  const int nA = (isz ? rank : rank - 32) * 32;  // stage-A column base (32 cols)
  const int nB = rank * 16;                      // stage-B column base (16 cols)
  const u16* __restrict__ WAsrc = isz ? Wzh : Wrh;
  const u16* __restrict__ PA = isz ? Pz : Pr;
  u32* ctr = bar + (u64)g * 64;  // counters 256B apart

  // Persistent weight slices -> LDS (once).
  for (int e = tid * 8; e < 32 * HID; e += 256 * 8) {
    int row = e >> 10, col = e & (HID - 1);
    *reinterpret_cast<bf16x8*>(&WA[row * PADW + col]) =
        *reinterpret_cast<const bf16x8*>(&WAsrc[(u64)(nA + row) * HID + col]);
  }
  for (int e = tid * 8; e < 16 * HID; e += 256 * 8) {
    int row = e >> 10, col = e & (HID - 1);
    *reinterpret_cast<bf16x8*>(&WB[row * PADW + col]) =
        *reinterpret_cast<const bf16x8*>(&Whh[(u64)(nB + row) * HID + col]);
  }
  for (int e = tid; e < 16 * PADW / 2; e += 256) reinterpret_cast<u32*>(HX)[e] = 0u;
  __syncthreads();

  u32 phase = 0;
  const int tile = wid & 1, khalf = wid >> 1;
  const int ct = tile * 16;

  for (int t = 0; t < TLEN; ++t) {
    // HX <- h_{t-1} (zeros already present for t==0)
    if (t > 0) {
      for (int e = tid * 8; e < GB * HID; e += 256 * 8) {
        int row = e >> 10, col = e & (HID - 1);
        *reinterpret_cast<bf16x8*>(&HX[row * PADW + col]) =
            *reinterpret_cast<const bf16x8*>(&PhH[((u64)(b0 + row) * TLEN + (t - 1)) * HID + col]);
      }
      __syncthreads();
    }

    // ---- stage A: gate = sigmoid(h @ W.T + P); write z or r*h ----
    f32x4 acc = {0.f, 0.f, 0.f, 0.f};
    {
      const int kb = khalf * 512 + 8 * (lane >> 4);
      const int ar = (lane & 15) * PADW;
      const int brr = (ct + (lane & 15)) * PADW;
#pragma unroll
      for (int ks = 0; ks < 16; ++ks) {
        bf16x8 a = *reinterpret_cast<const bf16x8*>(&HX[ar + kb + ks * 32]);
        bf16x8 b = *reinterpret_cast<const bf16x8*>(&WA[brr + kb + ks * 32]);
        acc = __builtin_amdgcn_mfma_f32_16x16x32_bf16(a, b, acc, 0, 0, 0);
      }
    }
    if (khalf == 1) {
#pragma unroll
      for (int q = 0; q < 4; ++q) RED[(tile * 64 + lane) * 4 + q] = acc[q];
    }
    __syncthreads();
    if (khalf == 0) {
      int col = nA + ct + (lane & 15);
#pragma unroll
      for (int q = 0; q < 4; ++q) {
        int m = 4 * (lane >> 4) + q;
        float pre = acc[q] + RED[(tile * 64 + lane) * 4 + q] +
                    bf2f(PA[((u64)(b0 + m) * TLEN + t) * HID + col]);
        float s = 1.f / (1.f + __expf(-pre));
        if (isz) {
          zbuf[(g * GB + m) * HID + col] = f2bf(s);
        } else {
          float h = bf2f(HX[m * PADW + col]);
          rhbuf[(g * GB + m) * HID + col] = f2bf(s * h);
        }
      }
    }
    group_barrier(ctr, RWGS * (++phase));

    // ---- stage B: htilde = tanh(rh @ Whh.T + Ph); h' = (1-z)h + z*htilde ----
    float hv[4] = {0, 0, 0, 0}, zv[4] = {0, 0, 0, 0};
    if (wid == 0) {
      int col = nB + (lane & 15);
#pragma unroll
      for (int q = 0; q < 4; ++q) {
        int m = 4 * (lane >> 4) + q;
        hv[q] = bf2f(HX[m * PADW + col]);
        zv[q] = bf2f(zbuf[(g * GB + m) * HID + col]);
      }
    }
    __syncthreads();  // everyone done reading h from HX
    for (int e = tid * 8; e < GB * HID; e += 256 * 8) {
      int row = e >> 10, col = e & (HID - 1);
      *reinterpret_cast<bf16x8*>(&HX[row * PADW + col]) =
          *reinterpret_cast<const bf16x8*>(&rhbuf[(u64)(g * GB + row) * HID + col]);
    }
    __syncthreads();

    f32x4 acc2 = {0.f, 0.f, 0.f, 0.f};
    {
      const int kb = wid * 256 + 8 * (lane >> 4);
      const int ar = (lane & 15) * PADW;
#pragma unroll
      for (int ks = 0; ks < 8; ++ks) {
        bf16x8 a = *reinterpret_cast<const bf16x8*>(&HX[ar + kb + ks * 32]);
        bf16x8 b = *reinterpret_cast<const bf16x8*>(&WB[ar + kb + ks * 32]);
        acc2 = __builtin_amdgcn_mfma_f32_16x16x32_bf16(a, b, acc2, 0, 0, 0);
      }
    }
    if (wid > 0) {
#pragma unroll
      for (int q = 0; q < 4; ++q) RED[((wid - 1) * 64 + lane) * 4 + q] = acc2[q];
    }
    __syncthreads();
    if (wid == 0) {
      int col = nB + (lane & 15);
#pragma unroll
      for (int q = 0; q < 4; ++q) {
        int m = 4 * (lane >> 4) + q;
        u64 idx = ((u64)(b0 + m) * TLEN + t) * HID + col;
        float pre = acc2[q] + RED[(0 * 64 + lane) * 4 + q] + RED[(1 * 64 + lane) * 4 + q] +
                    RED[(2 * 64 + lane) * 4 + q] + bf2f(PhH[idx]);
        float e2 = __expf(2.f * pre);
        float th = 1.f - 2.f / (e2 + 1.f);  // tanh, inf-safe
        float hn = (1.f - zv[q]) * hv[q] + zv[q] * th;
        PhH[idx] = f2bf(hn);  // in-place: Ph[t] consumed -> h[t] stored
      }
    }
    group_barrier(ctr, RWGS * (++phase));
  }
}

// ---------------- host ----------------
extern "C" void kernel_launch(void* const* d_in, const int* in_sizes, int n_in,
                              void* d_out, int out_size, void* d_ws, size_t ws_size,
                              hipStream_t stream) {
  const float* word = (const float*)d_in[0];
  const float* Wz = (const float*)d_in[1];
  const float* bz = (const float*)d_in[2];
  const float* Wr = (const float*)d_in[3];
  const float* br = (const float*)d_in[4];
  const float* Wh = (const float*)d_in[5];
  const float* bh = (const float*)d_in[6];
  const float* Wy = (const float*)d_in[7];
  const float* by = (const float*)d_in[8];
  float* out = (float*)d_out;
  (void)in_sizes; (void)n_in; (void)out_size; (void)ws_size;

  char* ws = (char*)d_ws;
  size_t off = 0;
  auto alloc = [&](size_t bytes) {
    char* p = ws + off;
    off += (bytes + 255) & ~(size_t)255;
    return p;
  };
  u32* bar  = (u32*)alloc(1024);                       // 4 counters, 256B apart
  u16* WzhB = (u16*)alloc((size_t)HID * HID * 2);
  u16* WrhB = (u16*)alloc((size_t)HID * HID * 2);
  u16* WhhB = (u16*)alloc((size_t)HID * HID * 2);
  u16* WzxB = (u16*)alloc((size_t)HID * EMB * 2);
  u16* WrxB = (u16*)alloc((size_t)HID * EMB * 2);
  u16* WhxB = (u16*)alloc((size_t)HID * EMB * 2);
  u16* WyB  = (u16*)alloc((size_t)EMB * HID * 2);
  u16* Pr   = (u16*)alloc((size_t)BATCHN * TLEN * HID * 2);
  u16* PhH  = (u16*)alloc((size_t)BATCHN * TLEN * HID * 2);
  u16* zbuf = (u16*)alloc((size_t)GROUPS * GB * HID * 2);
  u16* rhbf = (u16*)alloc((size_t)GROUPS * GB * HID * 2);
  // total ws use ~138 MiB
  u16* Pz = (u16*)d_out;  // 32768*1024 bf16 == 32768*512 fp32: exact overlay; dead
                          // before out_gemm overwrites d_out.

  hipMemsetAsync(bar, 0, 1024, stream);

  convert_gate_w<<<(HID * CAT + 255) / 256, 256, 0, stream>>>(Wz, WzhB, WzxB);
  convert_gate_w<<<(HID * CAT + 255) / 256, 256, 0, stream>>>(Wr, WrhB, WrxB);
  convert_gate_w<<<(HID * CAT + 255) / 256, 256, 0, stream>>>(Wh, WhhB, WhxB);
  convert_wy<<<(EMB * HID + 255) / 256, 256, 0, stream>>>(Wy, WyB);

  dim3 pg(512, 16);
  proj_kernel<<<pg, 256, 0, stream>>>(word, WzxB, bz, Pz);
  proj_kernel<<<pg, 256, 0, stream>>>(word, WrxB, br, Pr);
  proj_kernel<<<pg, 256, 0, stream>>>(word, WhxB, bh, PhH);

  gru_persistent<<<dim3(256), dim3(256), 0, stream>>>(WzhB, WrhB, WhhB, Pz, Pr, PhH,
                                                      zbuf, rhbf, bar);

  out_gemm<<<dim3(512, 8), 256, 0, stream>>>(PhH, WyB, by, out);
}

// Round 3
// 11781.762 us; speedup vs baseline: 1.9176x; 1.9176x over previous
//
#include <hip/hip_runtime.h>
#include <hip/hip_bf16.h>

// GRU restructured (v3):
//   Phase 0: fp32->bf16 weight conversion; gate weights split into h-part/x-part.
//   Phase 1: Pg[b,t,:] = word[b,t-1,:] @ Wg_x.T + bg  (parallel GEMM; t==0 -> bias only)
//            Pz -> d_out overlay (dead before out_gemm), Pr -> ws, Ph -> ws (PhH, in-place).
//   Phase 2: persistent kernel, 4 groups x 16 WGs (64 CUs, 1 WG/CU):
//            - stage-A weights (Wzh,Wrh slices) live in VGPRs (256/wave),
//              Whh slice (64 rows) in LDS. z stays CU-local (LDS zbufL).
//            - per step: A: z,r=sigmoid(h@W.T+P); rh=r*h -> global rhbuf | flag-barrier
//                        B: htilde=tanh(rh@Whh.T+Ph); h=(1-z)h+z*htilde -> PhH[t] | flag-barrier
//            - barrier = per-WG release-store flag + 16-lane parallel poll (no contention).
//   Phase 3: out = PhH @ Wy.T + by (parallel GEMM, fp32 -> d_out).

#define EMB 512
#define HID 1024
#define BATCHN 64
#define TLEN 512
#define CAT 1536
#define GROUPS 4
#define GB 16
#define WPG 16            // WGs per group
#define WHH_LD (HID + 8)  // padded LDS leading dim for Whh
#define GPAD 8

typedef __attribute__((ext_vector_type(8))) short bf16x8;
typedef __attribute__((ext_vector_type(4))) short s16x4;
typedef __attribute__((ext_vector_type(4))) float f32x4;
typedef unsigned int u32;
typedef unsigned long long u64;
typedef unsigned short u16;

__device__ __forceinline__ float bf2f(u16 u) {
  union { float f; u32 i; } v; v.i = ((u32)u) << 16; return v.f;
}
__device__ __forceinline__ u16 f2bf(float f) {
  union { float f; u32 i; } v; v.f = f;
  u32 r = v.i + 0x7fffu + ((v.i >> 16) & 1u);
  return (u16)(r >> 16);
}

// ---------------- phase 0: weight conversion ----------------
__global__ __launch_bounds__(256) void convert_gate_w(const float* __restrict__ W,
                                                      u16* __restrict__ Wh_,
                                                      u16* __restrict__ Wx_) {
  int i = blockIdx.x * 256 + threadIdx.x;
  if (i >= HID * CAT) return;
  int row = i / CAT, col = i - row * CAT;
  u16 v = f2bf(W[i]);
  if (col < HID) Wh_[row * HID + col] = v;
  else           Wx_[row * EMB + (col - HID)] = v;
}

__global__ __launch_bounds__(256) void convert_wy(const float* __restrict__ W, u16* __restrict__ Wy_) {
  int i = blockIdx.x * 256 + threadIdx.x;
  if (i < EMB * HID) Wy_[i] = f2bf(W[i]);
}

// ---------------- phase 1: P = shift(word) @ Wx.T + bias ----------------
__global__ __launch_bounds__(256) void proj_kernel(const float* __restrict__ word,
                                                   const u16* __restrict__ Wx,
                                                   const float* __restrict__ bias,
                                                   u16* __restrict__ P) {
  __shared__ __align__(16) u16 As[64][64 + GPAD];
  __shared__ __align__(16) u16 Bs[64][64 + GPAD];
  const int tid = threadIdx.x;
  const int wid = tid >> 6, lane = tid & 63;
  const int m0 = blockIdx.x * 64, n0 = blockIdx.y * 64;
  const int mw = (wid >> 1) * 32, nw = (wid & 1) * 32;
  f32x4 acc[2][2] = {};
  for (int k0 = 0; k0 < EMB; k0 += 64) {
#pragma unroll
    for (int it = 0; it < 4; ++it) {
      int e = (it * 256 + tid) * 4;
      int row = e >> 6, col = e & 63;
      int R = m0 + row;
      float4 a = make_float4(0.f, 0.f, 0.f, 0.f);
      if ((R & (TLEN - 1)) != 0)
        a = *reinterpret_cast<const float4*>(&word[(u64)(R - 1) * EMB + k0 + col]);
      s16x4 vv;
      vv[0] = (short)f2bf(a.x); vv[1] = (short)f2bf(a.y);
      vv[2] = (short)f2bf(a.z); vv[3] = (short)f2bf(a.w);
      *reinterpret_cast<s16x4*>(&As[row][col]) = vv;
    }
#pragma unroll
    for (int it = 0; it < 2; ++it) {
      int e = (it * 256 + tid) * 8;
      int row = e >> 6, col = e & 63;
      *reinterpret_cast<bf16x8*>(&Bs[row][col]) =
          *reinterpret_cast<const bf16x8*>(&Wx[(u64)(n0 + row) * EMB + k0 + col]);
    }
    __syncthreads();
#pragma unroll
    for (int kk = 0; kk < 2; ++kk) {
      const int kb = kk * 32 + 8 * (lane >> 4);
#pragma unroll
      for (int i = 0; i < 2; ++i) {
        bf16x8 a = *reinterpret_cast<const bf16x8*>(&As[mw + i * 16 + (lane & 15)][kb]);
#pragma unroll
        for (int j = 0; j < 2; ++j) {
          bf16x8 b = *reinterpret_cast<const bf16x8*>(&Bs[nw + j * 16 + (lane & 15)][kb]);
          acc[i][j] = __builtin_amdgcn_mfma_f32_16x16x32_bf16(a, b, acc[i][j], 0, 0, 0);
        }
      }
    }
    __syncthreads();
  }
#pragma unroll
  for (int i = 0; i < 2; ++i)
#pragma unroll
    for (int j = 0; j < 2; ++j) {
      int col = n0 + nw + j * 16 + (lane & 15);
      float bv = bias[col];
#pragma unroll
      for (int q = 0; q < 4; ++q) {
        int row = m0 + mw + i * 16 + 4 * (lane >> 4) + q;
        P[(u64)row * HID + col] = f2bf(acc[i][j][q] + bv);
      }
    }
}

// ---------------- phase 3: out = H @ Wy.T + by (fp32 out) ----------------
__global__ __launch_bounds__(256) void out_gemm(const u16* __restrict__ H,
                                                const u16* __restrict__ Wy,
                                                const float* __restrict__ by,
                                                float* __restrict__ out) {
  __shared__ __align__(16) u16 As[64][64 + GPAD];
  __shared__ __align__(16) u16 Bs[64][64 + GPAD];
  const int tid = threadIdx.x;
  const int wid = tid >> 6, lane = tid & 63;
  const int m0 = blockIdx.x * 64, n0 = blockIdx.y * 64;
  const int mw = (wid >> 1) * 32, nw = (wid & 1) * 32;
  f32x4 acc[2][2] = {};
  for (int k0 = 0; k0 < HID; k0 += 64) {
#pragma unroll
    for (int it = 0; it < 2; ++it) {
      int e = (it * 256 + tid) * 8;
      int row = e >> 6, col = e & 63;
      *reinterpret_cast<bf16x8*>(&As[row][col]) =
          *reinterpret_cast<const bf16x8*>(&H[(u64)(m0 + row) * HID + k0 + col]);
      *reinterpret_cast<bf16x8*>(&Bs[row][col]) =
          *reinterpret_cast<const bf16x8*>(&Wy[(u64)(n0 + row) * HID + k0 + col]);
    }
    __syncthreads();
#pragma unroll
    for (int kk = 0; kk < 2; ++kk) {
      const int kb = kk * 32 + 8 * (lane >> 4);
#pragma unroll
      for (int i = 0; i < 2; ++i) {
        bf16x8 a = *reinterpret_cast<const bf16x8*>(&As[mw + i * 16 + (lane & 15)][kb]);
#pragma unroll
        for (int j = 0; j < 2; ++j) {
          bf16x8 b = *reinterpret_cast<const bf16x8*>(&Bs[nw + j * 16 + (lane & 15)][kb]);
          acc[i][j] = __builtin_amdgcn_mfma_f32_16x16x32_bf16(a, b, acc[i][j], 0, 0, 0);
        }
      }
    }
    __syncthreads();
  }
#pragma unroll
  for (int i = 0; i < 2; ++i)
#pragma unroll
    for (int j = 0; j < 2; ++j) {
      int col = n0 + nw + j * 16 + (lane & 15);
      float bv = by[col];
#pragma unroll
      for (int q = 0; q < 4; ++q) {
        int row = m0 + mw + i * 16 + 4 * (lane >> 4) + q;
        out[(u64)row * EMB + col] = acc[i][j][q] + bv;
      }
    }
}

// ---------------- phase 2: persistent recurrent kernel ----------------
// Flag barrier: each WG release-stores its phase number to its own 64B slot;
// wave 0's lanes 0..WPG-1 poll all slots in parallel. Thread-0-side
// __threadfence() (L2 writeback, covers the whole WG's prior stores since they
// share the CU's L2 path) before the flag store; agent-acquire fence by all
// threads after (invalidate stale L1/L2 lines).
__device__ __forceinline__ void group_barrier(u32* gflags, int rank, u32 target) {
  __syncthreads();
  if (threadIdx.x < 64) {
    const int lane = threadIdx.x;
    if (lane == rank) {
      __threadfence();
      __hip_atomic_store(&gflags[rank * 16], target, __ATOMIC_RELEASE, __HIP_MEMORY_SCOPE_AGENT);
    }
    u32* addr = &gflags[(lane & (WPG - 1)) * 16];
    const int active = (lane < WPG) ? 1 : 0;
    for (;;) {
      u32 v = __hip_atomic_load(addr, __ATOMIC_ACQUIRE, __HIP_MEMORY_SCOPE_AGENT);
      if (!__any(active & (v < target ? 1 : 0))) break;
      __builtin_amdgcn_s_sleep(1);
    }
  }
  __syncthreads();
  __builtin_amdgcn_fence(__ATOMIC_ACQUIRE, "agent");
}

__global__ __launch_bounds__(256, 1) void gru_persistent(
    const u16* __restrict__ Wzh, const u16* __restrict__ Wrh, const u16* __restrict__ Whh,
    const u16* __restrict__ Pz, const u16* __restrict__ Pr, u16* __restrict__ PhH,
    u16* __restrict__ rhbuf, u32* flags) {
  // LDS: WHH 64*1032*2 = 132096 + zbufL 2112 = ~134 KB -> 1 WG/CU.
  __shared__ __align__(16) u16 WHH[64 * WHH_LD];
  __shared__ __align__(16) u16 zbufL[16 * 66];

  const int tid = threadIdx.x;
  const int wid = tid >> 6;
  const int lane = tid & 63;
  const int g = blockIdx.x & (GROUPS - 1);
  const int w = blockIdx.x >> 2;  // 0..15
  const int b0 = g * GB;
  const int gate = wid >> 1;          // 0 = z, 1 = r
  const int half = wid & 1;
  const int cw = 64 * w + 32 * half;  // stage-A col base (32 cols, 2 N-tiles)
  const int colB = 64 * w + 16 * wid + (lane & 15);  // stage-B col (1 N-tile)
  const u16* __restrict__ WAsrc = gate ? Wrh : Wzh;
  const u16* __restrict__ PA = gate ? Pr : Pz;
  u32* gflags = flags + g * (WPG * 16);

  // ---- stage-A weight slice -> VGPRs (256 regs/wave) ----
  bf16x8 wf[2][32];
#pragma unroll
  for (int s = 0; s < 32; ++s)
#pragma unroll
    for (int j = 0; j < 2; ++j)
      wf[j][s] = *reinterpret_cast<const bf16x8*>(
          WAsrc + (u64)(cw + 16 * j + (lane & 15)) * HID + 32 * s + (lane >> 4) * 8);

  // ---- Whh slice (64 rows) -> LDS ----
  for (int it = tid; it < 64 * HID / 8; it += 256) {
    int idx = it * 8;
    int row = idx >> 10, col = idx & (HID - 1);
    *reinterpret_cast<bf16x8*>(&WHH[row * WHH_LD + col]) =
        *reinterpret_cast<const bf16x8*>(Whh + (u64)(64 * w + row) * HID + col);
  }
  __syncthreads();

  u32 ph = 0;
  for (int t = 0; t < TLEN; ++t) {
    // ================= phase A =================
    // early loads (independent of MFMA): hprev for stage-B cols, P gate values
    float hprev[4];
#pragma unroll
    for (int q = 0; q < 4; ++q) {
      int m = 4 * (lane >> 4) + q;
      hprev[q] = (t > 0)
          ? bf2f(PhH[((u64)(b0 + m) * TLEN + (t - 1)) * HID + colB]) : 0.f;
    }
    float pA[2][4];
#pragma unroll
    for (int j = 0; j < 2; ++j)
#pragma unroll
      for (int q = 0; q < 4; ++q) {
        int m = 4 * (lane >> 4) + q;
        pA[j][q] = bf2f(PA[((u64)(b0 + m) * TLEN + t) * HID + cw + 16 * j + (lane & 15)]);
      }

    f32x4 acc0 = {0.f, 0.f, 0.f, 0.f}, acc1 = {0.f, 0.f, 0.f, 0.f};
    if (t > 0) {
      const u16* hrow = PhH + ((u64)(b0 + (lane & 15)) * TLEN + (t - 1)) * HID + (lane >> 4) * 8;
#pragma unroll
      for (int s = 0; s < 32; ++s) {
        bf16x8 a = *reinterpret_cast<const bf16x8*>(hrow + 32 * s);
        acc0 = __builtin_amdgcn_mfma_f32_16x16x32_bf16(a, wf[0][s], acc0, 0, 0, 0);
        acc1 = __builtin_amdgcn_mfma_f32_16x16x32_bf16(a, wf[1][s], acc1, 0, 0, 0);
      }
    }
#pragma unroll
    for (int j = 0; j < 2; ++j) {
#pragma unroll
      for (int q = 0; q < 4; ++q) {
        int m = 4 * (lane >> 4) + q;
        int col = cw + 16 * j + (lane & 15);
        float pre = (j == 0 ? acc0[q] : acc1[q]) + pA[j][q];
        float sg = 1.f / (1.f + __expf(-pre));
        if (gate == 0) {
          zbufL[m * 66 + (col - 64 * w)] = f2bf(sg);
        } else {
          float hval = (t > 0)
              ? bf2f(PhH[((u64)(b0 + m) * TLEN + (t - 1)) * HID + col]) : 0.f;
          rhbuf[(u64)(g * GB + m) * HID + col] = f2bf(sg * hval);
        }
      }
    }
    group_barrier(gflags, w, ++ph);

    // ================= phase B =================
    float pB[4];
    u64 idxB[4];
#pragma unroll
    for (int q = 0; q < 4; ++q) {
      int m = 4 * (lane >> 4) + q;
      idxB[q] = ((u64)(b0 + m) * TLEN + t) * HID + colB;
      pB[q] = bf2f(PhH[idxB[q]]);
    }
    f32x4 acc2 = {0.f, 0.f, 0.f, 0.f};
    {
      const u16* rrow = rhbuf + (u64)(g * GB + (lane & 15)) * HID + (lane >> 4) * 8;
      const u16* brow = &WHH[(16 * wid + (lane & 15)) * WHH_LD + (lane >> 4) * 8];
#pragma unroll
      for (int s = 0; s < 32; ++s) {
        bf16x8 a = *reinterpret_cast<const bf16x8*>(rrow + 32 * s);
        bf16x8 b = *reinterpret_cast<const bf16x8*>(brow + 32 * s);
        acc2 = __builtin_amdgcn_mfma_f32_16x16x32_bf16(a, b, acc2, 0, 0, 0);
      }
    }
#pragma unroll
    for (int q = 0; q < 4; ++q) {
      int m = 4 * (lane >> 4) + q;
      float pre = acc2[q] + pB[q];
      float e2 = __expf(2.f * pre);
      float th = 1.f - 2.f / (e2 + 1.f);  // tanh, inf-safe
      float zq = bf2f(zbufL[m * 66 + 16 * wid + (lane & 15)]);
      float hn = (1.f - zq) * hprev[q] + zq * th;
      PhH[idxB[q]] = f2bf(hn);  // in-place: Ph[t] consumed -> h[t]
    }
    group_barrier(gflags, w, ++ph);
  }
}

// ---------------- host ----------------
extern "C" void kernel_launch(void* const* d_in, const int* in_sizes, int n_in,
                              void* d_out, int out_size, void* d_ws, size_t ws_size,
                              hipStream_t stream) {
  const float* word = (const float*)d_in[0];
  const float* Wz = (const float*)d_in[1];
  const float* bz = (const float*)d_in[2];
  const float* Wr = (const float*)d_in[3];
  const float* br = (const float*)d_in[4];
  const float* Wh = (const float*)d_in[5];
  const float* bh = (const float*)d_in[6];
  const float* Wy = (const float*)d_in[7];
  const float* by = (const float*)d_in[8];
  float* out = (float*)d_out;
  (void)in_sizes; (void)n_in; (void)out_size; (void)ws_size;

  char* ws = (char*)d_ws;
  size_t off = 0;
  auto alloc = [&](size_t bytes) {
    char* p = ws + off;
    off += (bytes + 255) & ~(size_t)255;
    return p;
  };
  u32* flags = (u32*)alloc(4096);                      // 4 groups x 16 slots x 64B
  u16* WzhB = (u16*)alloc((size_t)HID * HID * 2);
  u16* WrhB = (u16*)alloc((size_t)HID * HID * 2);
  u16* WhhB = (u16*)alloc((size_t)HID * HID * 2);
  u16* WzxB = (u16*)alloc((size_t)HID * EMB * 2);
  u16* WrxB = (u16*)alloc((size_t)HID * EMB * 2);
  u16* WhxB = (u16*)alloc((size_t)HID * EMB * 2);
  u16* WyB  = (u16*)alloc((size_t)EMB * HID * 2);
  u16* Pr   = (u16*)alloc((size_t)BATCHN * TLEN * HID * 2);
  u16* PhH  = (u16*)alloc((size_t)BATCHN * TLEN * HID * 2);
  u16* rhbuf = (u16*)alloc((size_t)GROUPS * GB * HID * 2);
  // total ws use ~138 MiB
  u16* Pz = (u16*)d_out;  // overlay: 32768x1024 bf16 == 32768x512 fp32; dead
                          // before out_gemm overwrites d_out.

  hipMemsetAsync(flags, 0, 4096, stream);

  convert_gate_w<<<(HID * CAT + 255) / 256, 256, 0, stream>>>(Wz, WzhB, WzxB);
  convert_gate_w<<<(HID * CAT + 255) / 256, 256, 0, stream>>>(Wr, WrhB, WrxB);
  convert_gate_w<<<(HID * CAT + 255) / 256, 256, 0, stream>>>(Wh, WhhB, WhxB);
  convert_wy<<<(EMB * HID + 255) / 256, 256, 0, stream>>>(Wy, WyB);

  dim3 pg(512, 16);
  proj_kernel<<<pg, 256, 0, stream>>>(word, WzxB, bz, Pz);
  proj_kernel<<<pg, 256, 0, stream>>>(word, WrxB, br, Pr);
  proj_kernel<<<pg, 256, 0, stream>>>(word, WhxB, bh, PhH);

  gru_persistent<<<dim3(GROUPS * WPG), dim3(256), 0, stream>>>(WzhB, WrhB, WhhB, Pz, Pr, PhH,
                                                               rhbuf, flags);

  out_gemm<<<dim3(512, 8), 256, 0, stream>>>(PhH, WyB, by, out);
}

// Round 4
// 10840.409 us; speedup vs baseline: 2.0841x; 1.0868x over previous
//
#include <hip/hip_runtime.h>
#include <hip/hip_bf16.h>

// GRU restructured (v4): per-line device-coherent exchange, no cache fences.
//   Phase 0: fp32->bf16 weight conversion; gate weights split into h-part/x-part.
//   Phase 1: Pg[b,t,:] = word[b,t-1,:] @ Wg_x.T + bg  (parallel GEMM; t==0 -> bias only)
//            Pz -> d_out overlay (dead before out_gemm), Pr -> ws, Ph -> ws (PhH, in-place).
//   Phase 2: persistent kernel, 4 groups x 16 WGs (64 CUs, 1 WG/CU):
//            - stage-A weights in VGPRs/AGPRs, Whh slice in LDS
//            - exchanged data (h, rh) via relaxed AGENT-scope u64 atomics (sc1:
//              bypass non-coherent per-XCD L2, write-through/read-fresh at L3)
//            - gate outputs staged in LDS, flushed as coalesced u64 sc1 stores
//            - flag barrier: __syncthreads (drains vmcnt0 -> sc1 stores visible)
//              + relaxed flag store + relaxed poll. NO L1/L2 invalidates -> P
//              streams and weights stay cached.
//            - P-values for step t+1 prefetched (plain loads) before the poll.
//   Phase 3: out = PhH @ Wy.T + by (parallel GEMM, fp32 -> d_out).

#define EMB 512
#define HID 1024
#define BATCHN 64
#define TLEN 512
#define CAT 1536
#define GROUPS 4
#define GB 16
#define WPG 16            // WGs per group
#define WHH_LD (HID + 8)  // padded LDS leading dim for Whh
#define GPAD 8

typedef __attribute__((ext_vector_type(8))) short bf16x8;
typedef __attribute__((ext_vector_type(4))) short s16x4;
typedef __attribute__((ext_vector_type(4))) float f32x4;
typedef unsigned int u32;
typedef unsigned long long u64;
typedef unsigned short u16;

__device__ __forceinline__ float bf2f(u16 u) {
  union { float f; u32 i; } v; v.i = ((u32)u) << 16; return v.f;
}
__device__ __forceinline__ u16 f2bf(float f) {
  union { float f; u32 i; } v; v.f = f;
  u32 r = v.i + 0x7fffu + ((v.i >> 16) & 1u);
  return (u16)(r >> 16);
}

// Device-coherent (agent-scope, sc1) accessors: bypass non-coherent L2.
__device__ __forceinline__ u64 ld_dc(const u16* p) {
  return __hip_atomic_load((const u64*)p, __ATOMIC_RELAXED, __HIP_MEMORY_SCOPE_AGENT);
}
__device__ __forceinline__ void st_dc(u16* p, u64 v) {
  __hip_atomic_store((u64*)p, v, __ATOMIC_RELAXED, __HIP_MEMORY_SCOPE_AGENT);
}
__device__ __forceinline__ bf16x8 ld_dc16(const u16* p) {
  union { u64 q[2]; bf16x8 v; } u;
  u.q[0] = ld_dc(p);
  u.q[1] = ld_dc(p + 4);
  return u.v;
}

// ---------------- phase 0: weight conversion ----------------
__global__ __launch_bounds__(256) void convert_gate_w(const float* __restrict__ W,
                                                      u16* __restrict__ Wh_,
                                                      u16* __restrict__ Wx_) {
  int i = blockIdx.x * 256 + threadIdx.x;
  if (i >= HID * CAT) return;
  int row = i / CAT, col = i - row * CAT;
  u16 v = f2bf(W[i]);
  if (col < HID) Wh_[row * HID + col] = v;
  else           Wx_[row * EMB + (col - HID)] = v;
}

__global__ __launch_bounds__(256) void convert_wy(const float* __restrict__ W, u16* __restrict__ Wy_) {
  int i = blockIdx.x * 256 + threadIdx.x;
  if (i < EMB * HID) Wy_[i] = f2bf(W[i]);
}

// ---------------- phase 1: P = shift(word) @ Wx.T + bias ----------------
__global__ __launch_bounds__(256) void proj_kernel(const float* __restrict__ word,
                                                   const u16* __restrict__ Wx,
                                                   const float* __restrict__ bias,
                                                   u16* __restrict__ P) {
  __shared__ __align__(16) u16 As[64][64 + GPAD];
  __shared__ __align__(16) u16 Bs[64][64 + GPAD];
  const int tid = threadIdx.x;
  const int wid = tid >> 6, lane = tid & 63;
  const int m0 = blockIdx.x * 64, n0 = blockIdx.y * 64;
  const int mw = (wid >> 1) * 32, nw = (wid & 1) * 32;
  f32x4 acc[2][2] = {};
  for (int k0 = 0; k0 < EMB; k0 += 64) {
#pragma unroll
    for (int it = 0; it < 4; ++it) {
      int e = (it * 256 + tid) * 4;
      int row = e >> 6, col = e & 63;
      int R = m0 + row;
      float4 a = make_float4(0.f, 0.f, 0.f, 0.f);
      if ((R & (TLEN - 1)) != 0)
        a = *reinterpret_cast<const float4*>(&word[(u64)(R - 1) * EMB + k0 + col]);
      s16x4 vv;
      vv[0] = (short)f2bf(a.x); vv[1] = (short)f2bf(a.y);
      vv[2] = (short)f2bf(a.z); vv[3] = (short)f2bf(a.w);
      *reinterpret_cast<s16x4*>(&As[row][col]) = vv;
    }
#pragma unroll
    for (int it = 0; it < 2; ++it) {
      int e = (it * 256 + tid) * 8;
      int row = e >> 6, col = e & 63;
      *reinterpret_cast<bf16x8*>(&Bs[row][col]) =
          *reinterpret_cast<const bf16x8*>(&Wx[(u64)(n0 + row) * EMB + k0 + col]);
    }
    __syncthreads();
#pragma unroll
    for (int kk = 0; kk < 2; ++kk) {
      const int kb = kk * 32 + 8 * (lane >> 4);
#pragma unroll
      for (int i = 0; i < 2; ++i) {
        bf16x8 a = *reinterpret_cast<const bf16x8*>(&As[mw + i * 16 + (lane & 15)][kb]);
#pragma unroll
        for (int j = 0; j < 2; ++j) {
          bf16x8 b = *reinterpret_cast<const bf16x8*>(&Bs[nw + j * 16 + (lane & 15)][kb]);
          acc[i][j] = __builtin_amdgcn_mfma_f32_16x16x32_bf16(a, b, acc[i][j], 0, 0, 0);
        }
      }
    }
    __syncthreads();
  }
#pragma unroll
  for (int i = 0; i < 2; ++i)
#pragma unroll
    for (int j = 0; j < 2; ++j) {
      int col = n0 + nw + j * 16 + (lane & 15);
      float bv = bias[col];
#pragma unroll
      for (int q = 0; q < 4; ++q) {
        int row = m0 + mw + i * 16 + 4 * (lane >> 4) + q;
        P[(u64)row * HID + col] = f2bf(acc[i][j][q] + bv);
      }
    }
}

// ---------------- phase 3: out = H @ Wy.T + by (fp32 out) ----------------
__global__ __launch_bounds__(256) void out_gemm(const u16* __restrict__ H,
                                                const u16* __restrict__ Wy,
                                                const float* __restrict__ by,
                                                float* __restrict__ out) {
  __shared__ __align__(16) u16 As[64][64 + GPAD];
  __shared__ __align__(16) u16 Bs[64][64 + GPAD];
  const int tid = threadIdx.x;
  const int wid = tid >> 6, lane = tid & 63;
  const int m0 = blockIdx.x * 64, n0 = blockIdx.y * 64;
  const int mw = (wid >> 1) * 32, nw = (wid & 1) * 32;
  f32x4 acc[2][2] = {};
  for (int k0 = 0; k0 < HID; k0 += 64) {
#pragma unroll
    for (int it = 0; it < 2; ++it) {
      int e = (it * 256 + tid) * 8;
      int row = e >> 6, col = e & 63;
      *reinterpret_cast<bf16x8*>(&As[row][col]) =
          *reinterpret_cast<const bf16x8*>(&H[(u64)(m0 + row) * HID + k0 + col]);
      *reinterpret_cast<bf16x8*>(&Bs[row][col]) =
          *reinterpret_cast<const bf16x8*>(&Wy[(u64)(n0 + row) * HID + k0 + col]);
    }
    __syncthreads();
#pragma unroll
    for (int kk = 0; kk < 2; ++kk) {
      const int kb = kk * 32 + 8 * (lane >> 4);
#pragma unroll
      for (int i = 0; i < 2; ++i) {
        bf16x8 a = *reinterpret_cast<const bf16x8*>(&As[mw + i * 16 + (lane & 15)][kb]);
#pragma unroll
        for (int j = 0; j < 2; ++j) {
          bf16x8 b = *reinterpret_cast<const bf16x8*>(&Bs[nw + j * 16 + (lane & 15)][kb]);
          acc[i][j] = __builtin_amdgcn_mfma_f32_16x16x32_bf16(a, b, acc[i][j], 0, 0, 0);
        }
      }
    }
    __syncthreads();
  }
#pragma unroll
  for (int i = 0; i < 2; ++i)
#pragma unroll
    for (int j = 0; j < 2; ++j) {
      int col = n0 + nw + j * 16 + (lane & 15);
      float bv = by[col];
#pragma unroll
      for (int q = 0; q < 4; ++q) {
        int row = m0 + mw + i * 16 + 4 * (lane >> 4) + q;
        out[(u64)row * EMB + col] = acc[i][j][q] + bv;
      }
    }
}

// ---------------- phase 2: persistent recurrent kernel ----------------
// Flag barrier with NO cache maintenance:
//  - __syncthreads() drains vmcnt(0) -> all prior sc1 stores are globally
//    visible (write-through acked at the coherence point).
//  - relaxed agent flag store (sc1), relaxed agent poll (sc1, always fresh).
//  - monotonic targets make stale reads harmless.
__device__ __forceinline__ void group_barrier(u32* gflags, int rank, u32 target) {
  __syncthreads();
  asm volatile("" ::: "memory");
  if (threadIdx.x < 64) {
    if ((int)threadIdx.x == rank)
      __hip_atomic_store(&gflags[rank * 16], target, __ATOMIC_RELAXED, __HIP_MEMORY_SCOPE_AGENT);
    const int active = (threadIdx.x < WPG) ? 1 : 0;
    u32* addr = &gflags[((int)threadIdx.x & (WPG - 1)) * 16];
    for (;;) {
      u32 v = __hip_atomic_load(addr, __ATOMIC_RELAXED, __HIP_MEMORY_SCOPE_AGENT);
      if (!__any(active & ((v < target) ? 1 : 0))) break;
      __builtin_amdgcn_s_sleep(1);
    }
  }
  __syncthreads();
  asm volatile("" ::: "memory");
}

__global__ __launch_bounds__(256, 1) void gru_persistent(
    const u16* __restrict__ Wzh, const u16* __restrict__ Wrh, const u16* __restrict__ Whh,
    const u16* __restrict__ Pz, const u16* __restrict__ Pr, u16* __restrict__ PhH,
    u16* __restrict__ rhbuf, u32* flags) {
  // LDS: WHH 132096 + xfer 2304 + zL 2112 = ~136.5 KB -> 1 WG/CU.
  __shared__ __align__(16) u16 WHH[64 * WHH_LD];
  __shared__ __align__(16) u16 xfer[16][72];  // staging: h(t-1) -> rh -> h(t)
  __shared__ __align__(16) u16 zL[16][66];    // z-gate, CU-local

  const int tid = threadIdx.x;
  const int wid = tid >> 6;
  const int lane = tid & 63;
  const int g = blockIdx.x & (GROUPS - 1);
  const int w = blockIdx.x >> 2;  // 0..15
  const int b0 = g * GB;
  const int gate = wid >> 1;          // 0 = z, 1 = r
  const int half = wid & 1;
  const int cw = 64 * w + 32 * half;                 // stage-A col base (2 N-tiles)
  const int colB = 64 * w + 16 * wid + (lane & 15);  // stage-B col (1 N-tile)
  const u16* __restrict__ WAsrc = gate ? Wrh : Wzh;
  const u16* __restrict__ PA = gate ? Pr : Pz;
  u32* gflags = flags + g * (WPG * 16);

  // ---- stage-A weight slice -> registers (holds in VGPR/AGPR unified file) ----
  bf16x8 wf[2][32];
#pragma unroll
  for (int s = 0; s < 32; ++s)
#pragma unroll
    for (int j = 0; j < 2; ++j)
      wf[j][s] = *reinterpret_cast<const bf16x8*>(
          WAsrc + (u64)(cw + 16 * j + (lane & 15)) * HID + 32 * s + (lane >> 4) * 8);

  // ---- Whh slice (64 rows) -> LDS ----
  for (int it = tid; it < 64 * HID / 8; it += 256) {
    int idx = it * 8;
    int row = idx >> 10, col = idx & (HID - 1);
    *reinterpret_cast<bf16x8*>(&WHH[row * WHH_LD + col]) =
        *reinterpret_cast<const bf16x8*>(Whh + (u64)(64 * w + row) * HID + col);
  }
  // zero xfer (holds h(-1) = 0)
  for (int e = tid; e < 16 * 72 / 2; e += 256) reinterpret_cast<u32*>(xfer)[e] = 0u;
  __syncthreads();

  // prefetched P values for the CURRENT step
  float pAc[2][4], pBc[4];
#pragma unroll
  for (int j = 0; j < 2; ++j)
#pragma unroll
    for (int q = 0; q < 4; ++q) {
      int m = 4 * (lane >> 4) + q;
      pAc[j][q] = bf2f(PA[((u64)(b0 + m) * TLEN) * HID + cw + 16 * j + (lane & 15)]);
    }
#pragma unroll
  for (int q = 0; q < 4; ++q) {
    int m = 4 * (lane >> 4) + q;
    pBc[q] = bf2f(PhH[((u64)(b0 + m) * TLEN) * HID + colB]);
  }

  float hprev[4] = {0.f, 0.f, 0.f, 0.f};  // h(t-1) at (m, colB), carried in regs
  u32 ph = 0;

  for (int t = 0; t < TLEN; ++t) {
    // ================= phase A =================
    // r-waves: h(t-1) for own cols from LDS (for the r*h product)
    float hval[2][4];
    if (gate == 1) {
#pragma unroll
      for (int j = 0; j < 2; ++j)
#pragma unroll
        for (int q = 0; q < 4; ++q) {
          int m = 4 * (lane >> 4) + q;
          hval[j][q] = bf2f(xfer[m][32 * half + 16 * j + (lane & 15)]);
        }
    }

    f32x4 acc0 = {0.f, 0.f, 0.f, 0.f}, acc1 = {0.f, 0.f, 0.f, 0.f};
    if (t > 0) {
      const u16* hrow = PhH + ((u64)(b0 + (lane & 15)) * TLEN + (t - 1)) * HID + (lane >> 4) * 8;
#pragma unroll
      for (int s = 0; s < 32; ++s) {
        bf16x8 a = ld_dc16(hrow + 32 * s);  // device-coherent: fresh cross-XCD h
        acc0 = __builtin_amdgcn_mfma_f32_16x16x32_bf16(a, wf[0][s], acc0, 0, 0, 0);
        acc1 = __builtin_amdgcn_mfma_f32_16x16x32_bf16(a, wf[1][s], acc1, 0, 0, 0);
      }
    }
#pragma unroll
    for (int j = 0; j < 2; ++j) {
#pragma unroll
      for (int q = 0; q < 4; ++q) {
        int m = 4 * (lane >> 4) + q;
        float pre = (j == 0 ? acc0[q] : acc1[q]) + pAc[j][q];
        float sg = 1.f / (1.f + __expf(-pre));
        if (gate == 0) zL[m][32 * half + 16 * j + (lane & 15)] = f2bf(sg);
        else           xfer[m][32 * half + 16 * j + (lane & 15)] = f2bf(sg * hval[j][q]);
      }
    }
    __syncthreads();
    {  // flush rh -> rhbuf (coalesced u64 sc1 stores)
      int row = tid >> 4, ch = tid & 15;
      u64 v = *reinterpret_cast<const u64*>(&xfer[row][ch * 4]);
      st_dc(rhbuf + (u64)(g * GB + row) * HID + 64 * w + ch * 4, v);
    }
    group_barrier(gflags, w, ++ph);

    // ================= phase B =================
    f32x4 acc2 = {0.f, 0.f, 0.f, 0.f};
    {
      const u16* rrow = rhbuf + (u64)(g * GB + (lane & 15)) * HID + (lane >> 4) * 8;
      const u16* brow = &WHH[(16 * wid + (lane & 15)) * WHH_LD + (lane >> 4) * 8];
#pragma unroll
      for (int s = 0; s < 32; ++s) {
        bf16x8 a = ld_dc16(rrow + 32 * s);  // device-coherent rh
        bf16x8 b = *reinterpret_cast<const bf16x8*>(brow + 32 * s);
        acc2 = __builtin_amdgcn_mfma_f32_16x16x32_bf16(a, b, acc2, 0, 0, 0);
      }
    }
    float hn[4];
#pragma unroll
    for (int q = 0; q < 4; ++q) {
      int m = 4 * (lane >> 4) + q;
      float pre = acc2[q] + pBc[q];
      float e2 = __expf(2.f * pre);
      float th = 1.f - 2.f / (e2 + 1.f);  // tanh, inf-safe
      float zq = bf2f(zL[m][16 * wid + (lane & 15)]);
      hn[q] = (1.f - zq) * hprev[q] + zq * th;
      hprev[q] = hn[q];
      xfer[m][16 * wid + (lane & 15)] = f2bf(hn[q]);
    }
    __syncthreads();
    {  // flush h(t) -> PhH[t] (coalesced u64 sc1 stores)
      int row = tid >> 4, ch = tid & 15;
      u64 v = *reinterpret_cast<const u64*>(&xfer[row][ch * 4]);
      st_dc(PhH + ((u64)(b0 + row) * TLEN + t) * HID + 64 * w + ch * 4, v);
    }
    // prefetch P for t+1 (plain loads: L2-cacheable; latency hides under poll)
    {
      int tn = (t + 1 < TLEN) ? (t + 1) : t;
#pragma unroll
      for (int j = 0; j < 2; ++j)
#pragma unroll
        for (int q = 0; q < 4; ++q) {
          int m = 4 * (lane >> 4) + q;
          pAc[j][q] = bf2f(PA[((u64)(b0 + m) * TLEN + tn) * HID + cw + 16 * j + (lane & 15)]);
        }
#pragma unroll
      for (int q = 0; q < 4; ++q) {
        int m = 4 * (lane >> 4) + q;
        pBc[q] = bf2f(PhH[((u64)(b0 + m) * TLEN + tn) * HID + colB]);
      }
    }
    group_barrier(gflags, w, ++ph);
  }
}

// ---------------- host ----------------
extern "C" void kernel_launch(void* const* d_in, const int* in_sizes, int n_in,
                              void* d_out, int out_size, void* d_ws, size_t ws_size,
                              hipStream_t stream) {
  const float* word = (const float*)d_in[0];
  const float* Wz = (const float*)d_in[1];
  const float* bz = (const float*)d_in[2];
  const float* Wr = (const float*)d_in[3];
  const float* br = (const float*)d_in[4];
  const float* Wh = (const float*)d_in[5];
  const float* bh = (const float*)d_in[6];
  const float* Wy = (const float*)d_in[7];
  const float* by = (const float*)d_in[8];
  float* out = (float*)d_out;
  (void)in_sizes; (void)n_in; (void)out_size; (void)ws_size;

  char* ws = (char*)d_ws;
  size_t off = 0;
  auto alloc = [&](size_t bytes) {
    char* p = ws + off;
    off += (bytes + 255) & ~(size_t)255;
    return p;
  };
  u32* flags = (u32*)alloc(4096);                      // 4 groups x 16 slots x 64B
  u16* WzhB = (u16*)alloc((size_t)HID * HID * 2);
  u16* WrhB = (u16*)alloc((size_t)HID * HID * 2);
  u16* WhhB = (u16*)alloc((size_t)HID * HID * 2);
  u16* WzxB = (u16*)alloc((size_t)HID * EMB * 2);
  u16* WrxB = (u16*)alloc((size_t)HID * EMB * 2);
  u16* WhxB = (u16*)alloc((size_t)HID * EMB * 2);
  u16* WyB  = (u16*)alloc((size_t)EMB * HID * 2);
  u16* Pr   = (u16*)alloc((size_t)BATCHN * TLEN * HID * 2);
  u16* PhH  = (u16*)alloc((size_t)BATCHN * TLEN * HID * 2);
  u16* rhbuf = (u16*)alloc((size_t)GROUPS * GB * HID * 2);
  // total ws use ~138 MiB
  u16* Pz = (u16*)d_out;  // overlay: 32768x1024 bf16 == 32768x512 fp32; dead
                          // before out_gemm overwrites d_out.

  hipMemsetAsync(flags, 0, 4096, stream);

  convert_gate_w<<<(HID * CAT + 255) / 256, 256, 0, stream>>>(Wz, WzhB, WzxB);
  convert_gate_w<<<(HID * CAT + 255) / 256, 256, 0, stream>>>(Wr, WrhB, WrxB);
  convert_gate_w<<<(HID * CAT + 255) / 256, 256, 0, stream>>>(Wh, WhhB, WhxB);
  convert_wy<<<(EMB * HID + 255) / 256, 256, 0, stream>>>(Wy, WyB);

  dim3 pg(512, 16);
  proj_kernel<<<pg, 256, 0, stream>>>(word, WzxB, bz, Pz);
  proj_kernel<<<pg, 256, 0, stream>>>(word, WrxB, br, Pr);
  proj_kernel<<<pg, 256, 0, stream>>>(word, WhxB, bh, PhH);

  gru_persistent<<<dim3(GROUPS * WPG), dim3(256), 0, stream>>>(WzhB, WrhB, WhhB, Pz, Pr, PhH,
                                                               rhbuf, flags);

  out_gemm<<<dim3(512, 8), 256, 0, stream>>>(PhH, WyB, by, out);
}

// Round 5
// 5807.684 us; speedup vs baseline: 3.8901x; 1.8666x over previous
//
#include <hip/hip_runtime.h>
#include <hip/hip_bf16.h>

// GRU restructured (v5): MLP-fixed exchange via LDS cooperative staging.
//   Phase 0: fp32->bf16 weight conversion; gate weights split into h-part/x-part.
//   Phase 1: Pg[b,t,:] = word[b,t-1,:] @ Wg_x.T + bg  (parallel GEMM; t==0 -> bias only)
//            Pz -> d_out overlay (dead before out_gemm), Pr -> ws, Ph -> ws (PhH, in-place).
//   Phase 2: persistent kernel, 4 groups x 32 WGs (128 CUs, 1 WG/CU):
//            - each WG owns 32 cols; stage-A weights (z+r, 128 VGPR) and
//              stage-B weights (Whh, 64 VGPR, K-split x2) in registers
//            - h / rh exchanged via relaxed agent-scope u64 atomics (sc1);
//              cooperative batched load into LDS (16 independent u64/thread ->
//              one latency, one copy per CU); MFMA A-frags read from LDS
//            - flag barrier: syncthreads (drains vmcnt -> sc1 stores visible)
//              + relaxed flag store + parallel poll of 32 slots. No cache fences.
//            - P values for t+1 prefetched before the barrier poll.
//   Phase 3: out = PhH @ Wy.T + by (parallel GEMM, fp32 -> d_out).

#define EMB 512
#define HID 1024
#define BATCHN 64
#define TLEN 512
#define CAT 1536
#define GROUPS 4
#define GB 16
#define WPG 32            // WGs per group (each owns 32 cols)
#define HX_LD 1032        // LDS leading dim for h/rh staging (pad 8)
#define ZL_LD 34
#define XF_LD 36
#define GPAD 8

typedef __attribute__((ext_vector_type(8))) short bf16x8;
typedef __attribute__((ext_vector_type(4))) short s16x4;
typedef __attribute__((ext_vector_type(4))) float f32x4;
typedef unsigned int u32;
typedef unsigned long long u64;
typedef unsigned short u16;

__device__ __forceinline__ float bf2f(u16 u) {
  union { float f; u32 i; } v; v.i = ((u32)u) << 16; return v.f;
}
__device__ __forceinline__ u16 f2bf(float f) {
  union { float f; u32 i; } v; v.f = f;
  u32 r = v.i + 0x7fffu + ((v.i >> 16) & 1u);
  return (u16)(r >> 16);
}

// Device-coherent (agent-scope) accessors: bypass non-coherent per-XCD L2.
__device__ __forceinline__ u64 ld_dc(const u16* p) {
  return __hip_atomic_load((const u64*)p, __ATOMIC_RELAXED, __HIP_MEMORY_SCOPE_AGENT);
}
__device__ __forceinline__ void st_dc(u16* p, u64 v) {
  __hip_atomic_store((u64*)p, v, __ATOMIC_RELAXED, __HIP_MEMORY_SCOPE_AGENT);
}

// ---------------- phase 0: weight conversion ----------------
__global__ __launch_bounds__(256) void convert_gate_w(const float* __restrict__ W,
                                                      u16* __restrict__ Wh_,
                                                      u16* __restrict__ Wx_) {
  int i = blockIdx.x * 256 + threadIdx.x;
  if (i >= HID * CAT) return;
  int row = i / CAT, col = i - row * CAT;
  u16 v = f2bf(W[i]);
  if (col < HID) Wh_[row * HID + col] = v;
  else           Wx_[row * EMB + (col - HID)] = v;
}

__global__ __launch_bounds__(256) void convert_wy(const float* __restrict__ W, u16* __restrict__ Wy_) {
  int i = blockIdx.x * 256 + threadIdx.x;
  if (i < EMB * HID) Wy_[i] = f2bf(W[i]);
}

// ---------------- phase 1: P = shift(word) @ Wx.T + bias ----------------
__global__ __launch_bounds__(256) void proj_kernel(const float* __restrict__ word,
                                                   const u16* __restrict__ Wx,
                                                   const float* __restrict__ bias,
                                                   u16* __restrict__ P) {
  __shared__ __align__(16) u16 As[64][64 + GPAD];
  __shared__ __align__(16) u16 Bs[64][64 + GPAD];
  const int tid = threadIdx.x;
  const int wid = tid >> 6, lane = tid & 63;
  const int m0 = blockIdx.x * 64, n0 = blockIdx.y * 64;
  const int mw = (wid >> 1) * 32, nw = (wid & 1) * 32;
  f32x4 acc[2][2] = {};
  for (int k0 = 0; k0 < EMB; k0 += 64) {
#pragma unroll
    for (int it = 0; it < 4; ++it) {
      int e = (it * 256 + tid) * 4;
      int row = e >> 6, col = e & 63;
      int R = m0 + row;
      float4 a = make_float4(0.f, 0.f, 0.f, 0.f);
      if ((R & (TLEN - 1)) != 0)
        a = *reinterpret_cast<const float4*>(&word[(u64)(R - 1) * EMB + k0 + col]);
      s16x4 vv;
      vv[0] = (short)f2bf(a.x); vv[1] = (short)f2bf(a.y);
      vv[2] = (short)f2bf(a.z); vv[3] = (short)f2bf(a.w);
      *reinterpret_cast<s16x4*>(&As[row][col]) = vv;
    }
#pragma unroll
    for (int it = 0; it < 2; ++it) {
      int e = (it * 256 + tid) * 8;
      int row = e >> 6, col = e & 63;
      *reinterpret_cast<bf16x8*>(&Bs[row][col]) =
          *reinterpret_cast<const bf16x8*>(&Wx[(u64)(n0 + row) * EMB + k0 + col]);
    }
    __syncthreads();
#pragma unroll
    for (int kk = 0; kk < 2; ++kk) {
      const int kb = kk * 32 + 8 * (lane >> 4);
#pragma unroll
      for (int i = 0; i < 2; ++i) {
        bf16x8 a = *reinterpret_cast<const bf16x8*>(&As[mw + i * 16 + (lane & 15)][kb]);
#pragma unroll
        for (int j = 0; j < 2; ++j) {
          bf16x8 b = *reinterpret_cast<const bf16x8*>(&Bs[nw + j * 16 + (lane & 15)][kb]);
          acc[i][j] = __builtin_amdgcn_mfma_f32_16x16x32_bf16(a, b, acc[i][j], 0, 0, 0);
        }
      }
    }
    __syncthreads();
  }
#pragma unroll
  for (int i = 0; i < 2; ++i)
#pragma unroll
    for (int j = 0; j < 2; ++j) {
      int col = n0 + nw + j * 16 + (lane & 15);
      float bv = bias[col];
#pragma unroll
      for (int q = 0; q < 4; ++q) {
        int row = m0 + mw + i * 16 + 4 * (lane >> 4) + q;
        P[(u64)row * HID + col] = f2bf(acc[i][j][q] + bv);
      }
    }
}

// ---------------- phase 3: out = H @ Wy.T + by (fp32 out) ----------------
__global__ __launch_bounds__(256) void out_gemm(const u16* __restrict__ H,
                                                const u16* __restrict__ Wy,
                                                const float* __restrict__ by,
                                                float* __restrict__ out) {
  __shared__ __align__(16) u16 As[64][64 + GPAD];
  __shared__ __align__(16) u16 Bs[64][64 + GPAD];
  const int tid = threadIdx.x;
  const int wid = tid >> 6, lane = tid & 63;
  const int m0 = blockIdx.x * 64, n0 = blockIdx.y * 64;
  const int mw = (wid >> 1) * 32, nw = (wid & 1) * 32;
  f32x4 acc[2][2] = {};
  for (int k0 = 0; k0 < HID; k0 += 64) {
#pragma unroll
    for (int it = 0; it < 2; ++it) {
      int e = (it * 256 + tid) * 8;
      int row = e >> 6, col = e & 63;
      *reinterpret_cast<bf16x8*>(&As[row][col]) =
          *reinterpret_cast<const bf16x8*>(&H[(u64)(m0 + row) * HID + k0 + col]);
      *reinterpret_cast<bf16x8*>(&Bs[row][col]) =
          *reinterpret_cast<const bf16x8*>(&Wy[(u64)(n0 + row) * HID + k0 + col]);
    }
    __syncthreads();
#pragma unroll
    for (int kk = 0; kk < 2; ++kk) {
      const int kb = kk * 32 + 8 * (lane >> 4);
#pragma unroll
      for (int i = 0; i < 2; ++i) {
        bf16x8 a = *reinterpret_cast<const bf16x8*>(&As[mw + i * 16 + (lane & 15)][kb]);
#pragma unroll
        for (int j = 0; j < 2; ++j) {
          bf16x8 b = *reinterpret_cast<const bf16x8*>(&Bs[nw + j * 16 + (lane & 15)][kb]);
          acc[i][j] = __builtin_amdgcn_mfma_f32_16x16x32_bf16(a, b, acc[i][j], 0, 0, 0);
        }
      }
    }
    __syncthreads();
  }
#pragma unroll
  for (int i = 0; i < 2; ++i)
#pragma unroll
    for (int j = 0; j < 2; ++j) {
      int col = n0 + nw + j * 16 + (lane & 15);
      float bv = by[col];
#pragma unroll
      for (int q = 0; q < 4; ++q) {
        int row = m0 + mw + i * 16 + 4 * (lane >> 4) + q;
        out[(u64)row * EMB + col] = acc[i][j][q] + bv;
      }
    }
}

// ---------------- phase 2: persistent recurrent kernel ----------------
// Flag barrier, no cache maintenance (sc1 exchange handles coherence):
// syncthreads drains vmcnt -> prior sc1 stores globally visible; relaxed
// flag store; lanes 0..31 of wave 0 poll all 32 slots in parallel.
__device__ __forceinline__ void group_barrier(u32* gflags, int rank, u32 target) {
  __syncthreads();
  asm volatile("" ::: "memory");
  if (threadIdx.x < 64) {
    if ((int)threadIdx.x == rank)
      __hip_atomic_store(&gflags[rank * 16], target, __ATOMIC_RELAXED, __HIP_MEMORY_SCOPE_AGENT);
    const int active = (threadIdx.x < WPG) ? 1 : 0;
    u32* addr = &gflags[((int)threadIdx.x & (WPG - 1)) * 16];
    for (;;) {
      u32 v = __hip_atomic_load(addr, __ATOMIC_RELAXED, __HIP_MEMORY_SCOPE_AGENT);
      if (!__any(active & ((v < target) ? 1 : 0))) break;
      __builtin_amdgcn_s_sleep(1);
    }
  }
  __syncthreads();
  asm volatile("" ::: "memory");
}

__global__ __launch_bounds__(256, 1) void gru_persistent(
    const u16* __restrict__ Wzh, const u16* __restrict__ Wrh, const u16* __restrict__ Whh,
    const u16* __restrict__ Pz, const u16* __restrict__ Pr, u16* __restrict__ PhH,
    u16* __restrict__ rhbuf, u32* flags) {
  // LDS ~37.3 KB: hx (h/rh staging) + zL + xfer + RED.
  __shared__ __align__(16) u16 hx[16 * HX_LD];
  __shared__ __align__(16) u16 zL[16 * ZL_LD];
  __shared__ __align__(16) u16 xfer[16 * XF_LD];
  __shared__ __align__(16) float RED[2 * 64 * 4];

  const int tid = threadIdx.x;
  const int wid = tid >> 6;
  const int lane = tid & 63;
  const int g = blockIdx.x & (GROUPS - 1);
  const int w = blockIdx.x >> 2;  // 0..31, owns cols [32w, 32w+32)
  const int b0 = g * GB;
  const int j = wid & 1;            // 16-col tile within the 32
  const int gate = wid >> 1;        // stage A: 0 = z, 1 = r
  const int kh = wid >> 1;          // stage B: K-half
  const int colA = 32 * w + 16 * j + (lane & 15);
  const u16* __restrict__ PA = gate ? Pr : Pz;
  u32* gflags = flags + g * (WPG * 16);

  // ---- weights -> registers (unified VGPR/AGPR file) ----
  // stage A: this wave's 16 cols of Wzh or Wrh, full K: 128 regs
  bf16x8 wfA[32];
#pragma unroll
  for (int s = 0; s < 32; ++s)
    wfA[s] = *reinterpret_cast<const bf16x8*>(
        (gate ? Wrh : Wzh) + (u64)colA * HID + 32 * s + (lane >> 4) * 8);
  // stage B: this wave's 16 cols of Whh, K-half kh: 64 regs
  bf16x8 wfB[16];
#pragma unroll
  for (int s = 0; s < 16; ++s)
    wfB[s] = *reinterpret_cast<const bf16x8*>(
        Whh + (u64)colA * HID + kh * 512 + 32 * s + (lane >> 4) * 8);

  // zero hx (h(-1) = 0)
  for (int e = tid; e < 16 * HX_LD / 2; e += 256) reinterpret_cast<u32*>(hx)[e] = 0u;
  __syncthreads();

  // prefetched P values for the CURRENT step
  float pAc[4], pBc[4];
#pragma unroll
  for (int q = 0; q < 4; ++q) {
    int m = 4 * (lane >> 4) + q;
    pAc[q] = bf2f(PA[((u64)(b0 + m) * TLEN) * HID + colA]);
    pBc[q] = bf2f(PhH[((u64)(b0 + m) * TLEN) * HID + colA]);
  }

  float hprev[4] = {0.f, 0.f, 0.f, 0.f};  // h(t-1) at (m, colA), waves 0/1
  u32 ph = 0;

  for (int t = 0; t < TLEN; ++t) {
    // ---- cooperative load h(t-1) -> hx (batched sc1 u64, one latency) ----
    if (t > 0) {
      const u16* src = PhH + ((u64)(b0 + (tid >> 4)) * TLEN + (t - 1)) * HID + (tid & 15) * 64;
      u64 tmp[16];
#pragma unroll
      for (int i = 0; i < 16; ++i) tmp[i] = ld_dc(src + i * 4);
      u16* dst = &hx[(tid >> 4) * HX_LD + (tid & 15) * 64];
#pragma unroll
      for (int i = 0; i < 16; ++i) *reinterpret_cast<u64*>(dst + i * 4) = tmp[i];
      __syncthreads();
    }

    // ================= phase A: z,r = sigmoid(h @ W.T + P) =================
    f32x4 acc = {0.f, 0.f, 0.f, 0.f};
#pragma unroll
    for (int s = 0; s < 32; ++s) {
      bf16x8 a = *reinterpret_cast<const bf16x8*>(
          &hx[(lane & 15) * HX_LD + 32 * s + (lane >> 4) * 8]);
      acc = __builtin_amdgcn_mfma_f32_16x16x32_bf16(a, wfA[s], acc, 0, 0, 0);
    }
#pragma unroll
    for (int q = 0; q < 4; ++q) {
      int m = 4 * (lane >> 4) + q;
      float pre = acc[q] + pAc[q];
      float sg = 1.f / (1.f + __expf(-pre));
      if (gate == 0) {
        zL[m * ZL_LD + 16 * j + (lane & 15)] = f2bf(sg);
      } else {
        float hval = bf2f(hx[m * HX_LD + colA]);
        xfer[m * XF_LD + 16 * j + (lane & 15)] = f2bf(sg * hval);
      }
    }
    __syncthreads();
    {  // flush rh tile (16 rows x 32 cols) -> rhbuf, coalesced sc1 u64
      if (tid < 128) {
        int row = tid >> 3, ch = tid & 7;
        u64 v = *reinterpret_cast<const u64*>(&xfer[row * XF_LD + ch * 4]);
        st_dc(rhbuf + (u64)(g * GB + row) * HID + 32 * w + ch * 4, v);
      }
    }
    group_barrier(gflags, w, ++ph);

    // ---- cooperative load rh -> hx ----
    {
      const u16* src = rhbuf + (u64)(g * GB + (tid >> 4)) * HID + (tid & 15) * 64;
      u64 tmp[16];
#pragma unroll
      for (int i = 0; i < 16; ++i) tmp[i] = ld_dc(src + i * 4);
      u16* dst = &hx[(tid >> 4) * HX_LD + (tid & 15) * 64];
#pragma unroll
      for (int i = 0; i < 16; ++i) *reinterpret_cast<u64*>(dst + i * 4) = tmp[i];
      __syncthreads();
    }

    // ========= phase B: htilde = tanh(rh @ Whh.T + Ph); h update =========
    f32x4 acc2 = {0.f, 0.f, 0.f, 0.f};
#pragma unroll
    for (int s = 0; s < 16; ++s) {
      bf16x8 a = *reinterpret_cast<const bf16x8*>(
          &hx[(lane & 15) * HX_LD + kh * 512 + 32 * s + (lane >> 4) * 8]);
      acc2 = __builtin_amdgcn_mfma_f32_16x16x32_bf16(a, wfB[s], acc2, 0, 0, 0);
    }
    if (wid >= 2) *reinterpret_cast<f32x4*>(&RED[(j * 64 + lane) * 4]) = acc2;
    __syncthreads();
    if (wid < 2) {
      f32x4 part = *reinterpret_cast<const f32x4*>(&RED[(j * 64 + lane) * 4]);
#pragma unroll
      for (int q = 0; q < 4; ++q) {
        int m = 4 * (lane >> 4) + q;
        float pre = acc2[q] + part[q] + pBc[q];
        float e2 = __expf(2.f * pre);
        float th = 1.f - 2.f / (e2 + 1.f);  // tanh, inf-safe
        float zq = bf2f(zL[m * ZL_LD + 16 * j + (lane & 15)]);
        float hn = (1.f - zq) * hprev[q] + zq * th;
        hprev[q] = hn;
        xfer[m * XF_LD + 16 * j + (lane & 15)] = f2bf(hn);
      }
    }
    __syncthreads();
    {  // flush h(t) tile -> PhH[t] (in-place over Ph), coalesced sc1 u64
      if (tid < 128) {
        int row = tid >> 3, ch = tid & 7;
        u64 v = *reinterpret_cast<const u64*>(&xfer[row * XF_LD + ch * 4]);
        st_dc(PhH + ((u64)(b0 + row) * TLEN + t) * HID + 32 * w + ch * 4, v);
      }
    }
    // prefetch P for t+1 (plain cacheable loads; complete during the poll)
    {
      int tn = (t + 1 < TLEN) ? (t + 1) : t;
#pragma unroll
      for (int q = 0; q < 4; ++q) {
        int m = 4 * (lane >> 4) + q;
        pAc[q] = bf2f(PA[((u64)(b0 + m) * TLEN + tn) * HID + colA]);
        pBc[q] = bf2f(PhH[((u64)(b0 + m) * TLEN + tn) * HID + colA]);
      }
    }
    group_barrier(gflags, w, ++ph);
  }
}

// ---------------- host ----------------
extern "C" void kernel_launch(void* const* d_in, const int* in_sizes, int n_in,
                              void* d_out, int out_size, void* d_ws, size_t ws_size,
                              hipStream_t stream) {
  const float* word = (const float*)d_in[0];
  const float* Wz = (const float*)d_in[1];
  const float* bz = (const float*)d_in[2];
  const float* Wr = (const float*)d_in[3];
  const float* br = (const float*)d_in[4];
  const float* Wh = (const float*)d_in[5];
  const float* bh = (const float*)d_in[6];
  const float* Wy = (const float*)d_in[7];
  const float* by = (const float*)d_in[8];
  float* out = (float*)d_out;
  (void)in_sizes; (void)n_in; (void)out_size; (void)ws_size;

  char* ws = (char*)d_ws;
  size_t off = 0;
  auto alloc = [&](size_t bytes) {
    char* p = ws + off;
    off += (bytes + 255) & ~(size_t)255;
    return p;
  };
  u32* flags = (u32*)alloc(GROUPS * WPG * 16 * sizeof(u32));  // 8 KB
  u16* WzhB = (u16*)alloc((size_t)HID * HID * 2);
  u16* WrhB = (u16*)alloc((size_t)HID * HID * 2);
  u16* WhhB = (u16*)alloc((size_t)HID * HID * 2);
  u16* WzxB = (u16*)alloc((size_t)HID * EMB * 2);
  u16* WrxB = (u16*)alloc((size_t)HID * EMB * 2);
  u16* WhxB = (u16*)alloc((size_t)HID * EMB * 2);
  u16* WyB  = (u16*)alloc((size_t)EMB * HID * 2);
  u16* Pr   = (u16*)alloc((size_t)BATCHN * TLEN * HID * 2);
  u16* PhH  = (u16*)alloc((size_t)BATCHN * TLEN * HID * 2);
  u16* rhbuf = (u16*)alloc((size_t)GROUPS * GB * HID * 2);
  // total ws use ~138 MiB
  u16* Pz = (u16*)d_out;  // overlay: 32768x1024 bf16 == 32768x512 fp32; dead
                          // before out_gemm overwrites d_out.

  hipMemsetAsync(flags, 0, GROUPS * WPG * 16 * sizeof(u32), stream);

  convert_gate_w<<<(HID * CAT + 255) / 256, 256, 0, stream>>>(Wz, WzhB, WzxB);
  convert_gate_w<<<(HID * CAT + 255) / 256, 256, 0, stream>>>(Wr, WrhB, WrxB);
  convert_gate_w<<<(HID * CAT + 255) / 256, 256, 0, stream>>>(Wh, WhhB, WhxB);
  convert_wy<<<(EMB * HID + 255) / 256, 256, 0, stream>>>(Wy, WyB);

  dim3 pg(512, 16);
  proj_kernel<<<pg, 256, 0, stream>>>(word, WzxB, bz, Pz);
  proj_kernel<<<pg, 256, 0, stream>>>(word, WrxB, br, Pr);
  proj_kernel<<<pg, 256, 0, stream>>>(word, WhxB, bh, PhH);

  gru_persistent<<<dim3(GROUPS * WPG), dim3(256), 0, stream>>>(WzhB, WrhB, WhhB, Pz, Pr, PhH,
                                                               rhbuf, flags);

  out_gemm<<<dim3(512, 8), 256, 0, stream>>>(PhH, WyB, by, out);
}